// Round 7
// baseline (50.811 us; speedup 1.0000x reference)
//
#include <hip/hip_runtime.h>

#define N_PTS 128
#define FAR_DELTA 1e10f
#define EPS 1e-10f
#define RPB 16   // rays per 256-thread block: 8 segments x 2 rays each

// ---------------------------------------------------------------------------
// Volume rendering, coarsened: 32-lane segment renders TWO rays (ray, ray+8);
// all 10 dwordx4 loads issued up front for deep memory-level parallelism.
// depth_out written UNNORMALIZED; per-segment depth max (= fmax of the two
// rays' last samples, rows sorted) goes to blk_max — no atomics, no LDS,
// no __syncthreads.
//
// s at the global last point (sl==31, elem 3) is ~rho*1e10 and must NOT
// enter the scan totals ("inclusive - own" would cancel catastrophically);
// the reference's exclusive shift drops that element entirely, so we zero
// it in the total. No exclusive prefix ever contains it.
// ---------------------------------------------------------------------------
__device__ __forceinline__ float4 render_ray(
    float4 d4, float4 r4, float4 f0, float4 f1, float4 f2, int sl)
{
    // deltas
    float nd = __shfl_down(d4.x, 1, 32);
    float delta0 = d4.y - d4.x;
    float delta1 = d4.z - d4.y;
    float delta2 = d4.w - d4.z;
    float delta3 = (sl == 31) ? FAR_DELTA : (nd - d4.w);

    // s = rho*(delta+eps), local prefix, segmented scan of per-lane totals
    float s0 = r4.x * (delta0 + EPS);
    float s1 = r4.y * (delta1 + EPS);
    float s2 = r4.z * (delta2 + EPS);
    float s3 = r4.w * (delta3 + EPS);

    float p1 = s0;
    float p2 = s0 + s1;
    float p3 = p2 + s2;
    float tt = p3 + ((sl == 31) ? 0.0f : s3);  // drop the huge last element

    float inc = tt;
    #pragma unroll
    for (int off = 1; off < 32; off <<= 1) {
        float n = __shfl_up(inc, off, 32);
        if (sl >= off) inc += n;
    }
    float excl = inc - tt;

    // weights: trans * (1 - exp(-rho*delta + eps))
    float w0 = __expf(-excl)        * (1.0f - __expf(fmaf(-r4.x, delta0, EPS)));
    float w1 = __expf(-(excl + p1)) * (1.0f - __expf(fmaf(-r4.y, delta1, EPS)));
    float w2 = __expf(-(excl + p2)) * (1.0f - __expf(fmaf(-r4.z, delta2, EPS)));
    float w3 = __expf(-(excl + p3)) * (1.0f - __expf(fmaf(-r4.w, delta3, EPS)));

    // accumulate rgb + (unnormalized) depth
    float a0 = w0 * f0.x + w1 * f0.w + w2 * f1.z + w3 * f2.y;
    float a1 = w0 * f0.y + w1 * f1.x + w2 * f1.w + w3 * f2.z;
    float a2 = w0 * f0.z + w1 * f1.y + w2 * f2.x + w3 * f2.w;
    float ad = w0 * d4.x + w1 * d4.y + w2 * d4.z + w3 * d4.w;

    // 32-lane segmented sum reduce
    #pragma unroll
    for (int off = 16; off > 0; off >>= 1) {
        a0 += __shfl_xor(a0, off, 32);
        a1 += __shfl_xor(a1, off, 32);
        a2 += __shfl_xor(a2, off, 32);
        ad += __shfl_xor(ad, off, 32);
    }
    return make_float4(a0, a1, a2, ad);
}

__global__ __launch_bounds__(256) void vr_main(
    const float* __restrict__ depth,    // [n_rays, 128]
    const float* __restrict__ density,  // [n_rays, 128, 1]
    const float* __restrict__ feature,  // [n_rays, 128, 3]
    float* __restrict__ feat_out,       // [n_rays, 3]
    float* __restrict__ depth_out,      // [n_rays, 1] (unnormalized here)
    float* __restrict__ blk_max,        // [n_rays/2]
    int n_rays)
{
    const int t    = threadIdx.x;
    const int q    = t >> 5;                    // segment within block (0..7)
    const int sl   = t & 31;                    // lane within segment
    const int rayA = blockIdx.x * RPB + q;      // first ray
    const int rayB = rayA + 8;                  // second ray

    // ---- issue ALL loads up front (10 x dwordx4 per lane) ----
    const float4* dpA = (const float4*)(depth   + (size_t)rayA * N_PTS);
    const float4* rpA = (const float4*)(density + (size_t)rayA * N_PTS);
    const float4* fpA = (const float4*)(feature + (size_t)rayA * N_PTS * 3);
    const float4* dpB = (const float4*)(depth   + (size_t)rayB * N_PTS);
    const float4* rpB = (const float4*)(density + (size_t)rayB * N_PTS);
    const float4* fpB = (const float4*)(feature + (size_t)rayB * N_PTS * 3);

    float4 d4a = dpA[sl];
    float4 d4b = dpB[sl];
    float4 r4a = rpA[sl];
    float4 r4b = rpB[sl];
    float4 f0a = fpA[sl * 3 + 0];
    float4 f1a = fpA[sl * 3 + 1];
    float4 f2a = fpA[sl * 3 + 2];
    float4 f0b = fpB[sl * 3 + 0];
    float4 f1b = fpB[sl * 3 + 1];
    float4 f2b = fpB[sl * 3 + 2];

    float4 accA = render_ray(d4a, r4a, f0a, f1a, f2a, sl);
    float4 accB = render_ray(d4b, r4b, f0b, f1b, f2b, sl);

    if (sl == 0) {
        float* foA = feat_out + (size_t)rayA * 3;
        foA[0] = accA.x; foA[1] = accA.y; foA[2] = accA.z;
        depth_out[rayA] = accA.w;
        float* foB = feat_out + (size_t)rayB * 3;
        foB[0] = accB.x; foB[1] = accB.y; foB[2] = accB.z;
        depth_out[rayB] = accB.w;
    }

    // per-segment depth max (rows sorted -> last sample is the max)
    if (sl == 31)
        blk_max[blockIdx.x * 8 + q] = fmaxf(d4a.w, d4b.w);
}

// ---------------------------------------------------------------------------
// Epilogue: reduce per-segment maxes (L2-hot) and scale depth_out in place.
// Every block computes the same gmax redundantly, then scales its slice.
// ---------------------------------------------------------------------------
__global__ __launch_bounds__(256) void vr_epilogue(
    const float* __restrict__ blk_max, float* __restrict__ depth_out,
    int nb, int n_rays)
{
    const int t = threadIdx.x;

    float m = 0.0f;
    for (int i = t; i < nb; i += 256) m = fmaxf(m, blk_max[i]);
    #pragma unroll
    for (int off = 32; off > 0; off >>= 1)
        m = fmaxf(m, __shfl_xor(m, off, 64));

    __shared__ float wm[4];
    if ((t & 63) == 0) wm[t >> 6] = m;
    __syncthreads();
    float gm = fmaxf(fmaxf(wm[0], wm[1]), fmaxf(wm[2], wm[3]));

    int i = blockIdx.x * 256 + t;
    if (i < n_rays) depth_out[i] *= (1.0f / gm);
}

extern "C" void kernel_launch(void* const* d_in, const int* in_sizes, int n_in,
                              void* d_out, int out_size, void* d_ws, size_t ws_size,
                              hipStream_t stream)
{
    const float* depth   = (const float*)d_in[0];
    const float* density = (const float*)d_in[1];
    const float* feature = (const float*)d_in[2];

    const int n_rays = in_sizes[0] / N_PTS;

    float* out       = (float*)d_out;
    float* feat_out  = out;                        // [n_rays, 3]
    float* depth_out = out + (size_t)n_rays * 3;   // [n_rays, 1]
    float* blk_max   = (float*)d_ws;               // [n_rays/2] floats

    const int nb_main = n_rays / RPB;              // 4096 blocks
    const int nb_seg  = n_rays / 2;                // 32768 segment maxes

    vr_main<<<nb_main, 256, 0, stream>>>(depth, density, feature,
                                         feat_out, depth_out, blk_max, n_rays);

    const int eb = (n_rays + 255) / 256;           // 256 blocks
    vr_epilogue<<<eb, 256, 0, stream>>>(blk_max, depth_out, nb_seg, n_rays);
}

// Round 8
// 41.469 us; speedup vs baseline: 1.2253x; 1.2253x over previous
//
#include <hip/hip_runtime.h>

#define N_PTS 128
#define FAR_DELTA 1e10f
#define EPS 1e-10f
#define RPB 16   // rays per 256-thread block: 16 segments of 16 lanes

// ---------------------------------------------------------------------------
// Volume rendering: 16 lanes per ray, lane sl owns points 8sl..8sl+7 via
// 10 dwordx4 loads (160 B/lane) feeding ONE pipeline — deep per-lane MLP
// that the register allocator cannot split into serial phases (round-7
// lesson: two independent rays per segment got serialized at VGPR=32).
//
// Exclusive cumsum of s = rho*(delta+eps): 7-add local prefix + 4-step
// segmented shfl_up scan over per-lane totals (width 16).
//
// s at the global last point (sl==15, elem 7) is ~rho*1e10 and must NOT
// enter the scan totals ("inclusive - own" would cancel catastrophically);
// the reference's exclusive shift drops that element entirely, so we zero
// it in the total. No exclusive prefix ever contains it.
//
// depth_out is written UNNORMALIZED; per-wave depth max (4 rays/wave, rows
// sorted so ray max = last sample) goes to wave_max via 2 shfl_xor steps —
// no LDS, no __syncthreads, no atomics.
// ---------------------------------------------------------------------------
__global__ __launch_bounds__(256) void vr_main(
    const float* __restrict__ depth,    // [n_rays, 128]
    const float* __restrict__ density,  // [n_rays, 128, 1]
    const float* __restrict__ feature,  // [n_rays, 128, 3]
    float* __restrict__ feat_out,       // [n_rays, 3]
    float* __restrict__ depth_out,      // [n_rays, 1] (unnormalized here)
    float* __restrict__ wave_max,       // [n_rays/4]
    int n_rays)
{
    const int t   = threadIdx.x;
    const int sl  = t & 15;                          // lane within ray
    const int ray = (blockIdx.x * 256 + t) >> 4;     // 16 lanes per ray

    // ---- 10 dwordx4 loads, one pipeline ----
    const float4* dp4 = (const float4*)(depth   + (size_t)ray * N_PTS) + 2 * sl;
    const float4* rp4 = (const float4*)(density + (size_t)ray * N_PTS) + 2 * sl;
    const float4* fp4 = (const float4*)(feature + (size_t)ray * N_PTS * 3) + 6 * sl;

    float4 dA = dp4[0], dB = dp4[1];
    float4 rA = rp4[0], rB = rp4[1];
    float4 f0 = fp4[0], f1 = fp4[1], f2 = fp4[2];
    float4 f3 = fp4[3], f4 = fp4[4], f5 = fp4[5];

    // ---- deltas (8 points per lane) ----
    float nd = __shfl_down(dA.x, 1, 16);   // next lane's first depth
    float dl0 = dA.y - dA.x;
    float dl1 = dA.z - dA.y;
    float dl2 = dA.w - dA.z;
    float dl3 = dB.x - dA.w;
    float dl4 = dB.y - dB.x;
    float dl5 = dB.z - dB.y;
    float dl6 = dB.w - dB.z;
    float dl7 = (sl == 15) ? FAR_DELTA : (nd - dB.w);

    // ---- s = rho*(delta+eps), local exclusive prefix P_k ----
    float s0 = rA.x * (dl0 + EPS);
    float s1 = rA.y * (dl1 + EPS);
    float s2 = rA.z * (dl2 + EPS);
    float s3 = rA.w * (dl3 + EPS);
    float s4 = rB.x * (dl4 + EPS);
    float s5 = rB.y * (dl5 + EPS);
    float s6 = rB.z * (dl6 + EPS);
    float s7 = rB.w * (dl7 + EPS);

    float P1 = s0;
    float P2 = P1 + s1;
    float P3 = P2 + s2;
    float P4 = P3 + s3;
    float P5 = P4 + s4;
    float P6 = P5 + s5;
    float P7 = P6 + s6;
    float T  = P7 + ((sl == 15) ? 0.0f : s7);  // drop the huge last element

    // ---- 4-step segmented scan of per-lane totals (width 16) ----
    float inc = T;
    #pragma unroll
    for (int off = 1; off < 16; off <<= 1) {
        float n = __shfl_up(inc, off, 16);
        if (sl >= off) inc += n;
    }
    float ex = inc - T;   // sum of totals of lanes 0..sl-1 (all benign)

    // ---- weights: trans * (1 - exp(-rho*delta + eps)) ----
    float w0 = __expf(-ex)        * (1.0f - __expf(fmaf(-rA.x, dl0, EPS)));
    float w1 = __expf(-(ex + P1)) * (1.0f - __expf(fmaf(-rA.y, dl1, EPS)));
    float w2 = __expf(-(ex + P2)) * (1.0f - __expf(fmaf(-rA.z, dl2, EPS)));
    float w3 = __expf(-(ex + P3)) * (1.0f - __expf(fmaf(-rA.w, dl3, EPS)));
    float w4 = __expf(-(ex + P4)) * (1.0f - __expf(fmaf(-rB.x, dl4, EPS)));
    float w5 = __expf(-(ex + P5)) * (1.0f - __expf(fmaf(-rB.y, dl5, EPS)));
    float w6 = __expf(-(ex + P6)) * (1.0f - __expf(fmaf(-rB.z, dl6, EPS)));
    float w7 = __expf(-(ex + P7)) * (1.0f - __expf(fmaf(-rB.w, dl7, EPS)));

    // ---- accumulate rgb + (unnormalized) depth ----
    float a0 = w0*f0.x + w1*f0.w + w2*f1.z + w3*f2.y + w4*f3.x + w5*f3.w + w6*f4.z + w7*f5.y;
    float a1 = w0*f0.y + w1*f1.x + w2*f1.w + w3*f2.z + w4*f3.y + w5*f4.x + w6*f4.w + w7*f5.z;
    float a2 = w0*f0.z + w1*f1.y + w2*f2.x + w3*f2.w + w4*f3.z + w5*f4.y + w6*f5.x + w7*f5.w;
    float ad = w0*dA.x + w1*dA.y + w2*dA.z + w3*dA.w + w4*dB.x + w5*dB.y + w6*dB.z + w7*dB.w;

    // ---- 4-step segmented sum reduce (width 16) ----
    #pragma unroll
    for (int off = 8; off > 0; off >>= 1) {
        a0 += __shfl_xor(a0, off, 16);
        a1 += __shfl_xor(a1, off, 16);
        a2 += __shfl_xor(a2, off, 16);
        ad += __shfl_xor(ad, off, 16);
    }

    if (sl == 0) {
        float* fo = feat_out + (size_t)ray * 3;
        fo[0] = a0;
        fo[1] = a1;
        fo[2] = a2;
        depth_out[ray] = ad;
    }

    // ---- per-wave depth max (4 rays/wave; ray max = last sample) ----
    float cand = (sl == 15) ? dB.w : 0.0f;
    cand = fmaxf(cand, __shfl_xor(cand, 16, 64));
    cand = fmaxf(cand, __shfl_xor(cand, 32, 64));
    if ((t & 63) == 15)
        wave_max[(blockIdx.x * 256 + t) >> 6] = cand;
}

// ---------------------------------------------------------------------------
// Epilogue: reduce per-wave maxes (L2-hot, 16384 entries) and scale
// depth_out in place. Every block computes the same gmax redundantly.
// ---------------------------------------------------------------------------
__global__ __launch_bounds__(256) void vr_epilogue(
    const float* __restrict__ wave_max, float* __restrict__ depth_out,
    int nw, int n_rays)
{
    const int t = threadIdx.x;

    float m = 0.0f;
    for (int i = t; i < nw; i += 256) m = fmaxf(m, wave_max[i]);
    #pragma unroll
    for (int off = 32; off > 0; off >>= 1)
        m = fmaxf(m, __shfl_xor(m, off, 64));

    __shared__ float wm[4];
    if ((t & 63) == 0) wm[t >> 6] = m;
    __syncthreads();
    float gm = fmaxf(fmaxf(wm[0], wm[1]), fmaxf(wm[2], wm[3]));

    int i = blockIdx.x * 256 + t;
    if (i < n_rays) depth_out[i] *= (1.0f / gm);
}

extern "C" void kernel_launch(void* const* d_in, const int* in_sizes, int n_in,
                              void* d_out, int out_size, void* d_ws, size_t ws_size,
                              hipStream_t stream)
{
    const float* depth   = (const float*)d_in[0];
    const float* density = (const float*)d_in[1];
    const float* feature = (const float*)d_in[2];

    const int n_rays = in_sizes[0] / N_PTS;

    float* out       = (float*)d_out;
    float* feat_out  = out;                        // [n_rays, 3]
    float* depth_out = out + (size_t)n_rays * 3;   // [n_rays, 1]
    float* wave_max  = (float*)d_ws;               // [n_rays/4] floats

    const int nb_main = n_rays / RPB;              // 4096 blocks
    const int nw      = n_rays / 4;                // 16384 wave maxes

    vr_main<<<nb_main, 256, 0, stream>>>(depth, density, feature,
                                         feat_out, depth_out, wave_max, n_rays);

    const int eb = (n_rays + 255) / 256;           // 256 blocks
    vr_epilogue<<<eb, 256, 0, stream>>>(wave_max, depth_out, nw, n_rays);
}

// Round 9
// 41.163 us; speedup vs baseline: 1.2344x; 1.0074x over previous
//
#include <hip/hip_runtime.h>

#define N_PTS 128
#define FAR_DELTA 1e10f
#define EPS 1e-10f
#define RPB 16   // rays per 256-thread block: 16 segments of 16 lanes

// ---------------------------------------------------------------------------
// Volume rendering: 16 lanes per ray, lane sl owns points 8sl..8sl+7 via
// 10 dwordx4 loads (160 B/lane) issued as one clause for deep MLP.
//
// __launch_bounds__(256, 8): 8 waves/EU (= 32 waves/CU, the HW max) caps
// VGPR at 64 — enough to keep all 10 load results (40 VGPR) live, and
// removes the allocator's incentive to sink loads into serial phases
// (rounds 7/8 failure: default heuristic clamped VGPR=32 and serialized).
//
// Exclusive cumsum of s = rho*(delta+eps): 7-add local prefix + 4-step
// segmented shfl_up scan over per-lane totals (width 16).
//
// s at the global last point (sl==15, elem 7) is ~rho*1e10 and must NOT
// enter the scan totals ("inclusive - own" would cancel catastrophically);
// the reference's exclusive shift drops that element entirely, so we zero
// it in the total. No exclusive prefix ever contains it.
//
// depth_out written UNNORMALIZED; per-wave depth max (4 rays/wave, rows
// sorted so ray max = last sample) -> wave_max via 2 shfl_xor steps.
// ---------------------------------------------------------------------------
__global__ __launch_bounds__(256, 8) void vr_main(
    const float* __restrict__ depth,    // [n_rays, 128]
    const float* __restrict__ density,  // [n_rays, 128, 1]
    const float* __restrict__ feature,  // [n_rays, 128, 3]
    float* __restrict__ feat_out,       // [n_rays, 3]
    float* __restrict__ depth_out,      // [n_rays, 1] (unnormalized here)
    float* __restrict__ wave_max,       // [n_rays/4]
    int n_rays)
{
    const int t   = threadIdx.x;
    const int sl  = t & 15;                          // lane within ray
    const int ray = (blockIdx.x * 256 + t) >> 4;     // 16 lanes per ray

    // ---- 10 dwordx4 loads, one clause ----
    const float4* dp4 = (const float4*)(depth   + (size_t)ray * N_PTS) + 2 * sl;
    const float4* rp4 = (const float4*)(density + (size_t)ray * N_PTS) + 2 * sl;
    const float4* fp4 = (const float4*)(feature + (size_t)ray * N_PTS * 3) + 6 * sl;

    float4 dA = dp4[0], dB = dp4[1];
    float4 rA = rp4[0], rB = rp4[1];
    float4 f0 = fp4[0], f1 = fp4[1], f2 = fp4[2];
    float4 f3 = fp4[3], f4 = fp4[4], f5 = fp4[5];

    // ---- deltas (8 points per lane) ----
    float nd = __shfl_down(dA.x, 1, 16);   // next lane's first depth
    float dl0 = dA.y - dA.x;
    float dl1 = dA.z - dA.y;
    float dl2 = dA.w - dA.z;
    float dl3 = dB.x - dA.w;
    float dl4 = dB.y - dB.x;
    float dl5 = dB.z - dB.y;
    float dl6 = dB.w - dB.z;
    float dl7 = (sl == 15) ? FAR_DELTA : (nd - dB.w);

    // ---- s = rho*(delta+eps), local exclusive prefix P_k ----
    float s0 = rA.x * (dl0 + EPS);
    float s1 = rA.y * (dl1 + EPS);
    float s2 = rA.z * (dl2 + EPS);
    float s3 = rA.w * (dl3 + EPS);
    float s4 = rB.x * (dl4 + EPS);
    float s5 = rB.y * (dl5 + EPS);
    float s6 = rB.z * (dl6 + EPS);
    float s7 = rB.w * (dl7 + EPS);

    float P1 = s0;
    float P2 = P1 + s1;
    float P3 = P2 + s2;
    float P4 = P3 + s3;
    float P5 = P4 + s4;
    float P6 = P5 + s5;
    float P7 = P6 + s6;
    float T  = P7 + ((sl == 15) ? 0.0f : s7);  // drop the huge last element

    // ---- 4-step segmented scan of per-lane totals (width 16) ----
    float inc = T;
    #pragma unroll
    for (int off = 1; off < 16; off <<= 1) {
        float n = __shfl_up(inc, off, 16);
        if (sl >= off) inc += n;
    }
    float ex = inc - T;   // sum of totals of lanes 0..sl-1 (all benign)

    // ---- weights: trans * (1 - exp(-rho*delta + eps)) ----
    float w0 = __expf(-ex)        * (1.0f - __expf(fmaf(-rA.x, dl0, EPS)));
    float w1 = __expf(-(ex + P1)) * (1.0f - __expf(fmaf(-rA.y, dl1, EPS)));
    float w2 = __expf(-(ex + P2)) * (1.0f - __expf(fmaf(-rA.z, dl2, EPS)));
    float w3 = __expf(-(ex + P3)) * (1.0f - __expf(fmaf(-rA.w, dl3, EPS)));
    float w4 = __expf(-(ex + P4)) * (1.0f - __expf(fmaf(-rB.x, dl4, EPS)));
    float w5 = __expf(-(ex + P5)) * (1.0f - __expf(fmaf(-rB.y, dl5, EPS)));
    float w6 = __expf(-(ex + P6)) * (1.0f - __expf(fmaf(-rB.z, dl6, EPS)));
    float w7 = __expf(-(ex + P7)) * (1.0f - __expf(fmaf(-rB.w, dl7, EPS)));

    // ---- accumulate rgb + (unnormalized) depth ----
    float a0 = w0*f0.x + w1*f0.w + w2*f1.z + w3*f2.y + w4*f3.x + w5*f3.w + w6*f4.z + w7*f5.y;
    float a1 = w0*f0.y + w1*f1.x + w2*f1.w + w3*f2.z + w4*f3.y + w5*f4.x + w6*f4.w + w7*f5.z;
    float a2 = w0*f0.z + w1*f1.y + w2*f2.x + w3*f2.w + w4*f3.z + w5*f4.y + w6*f5.x + w7*f5.w;
    float ad = w0*dA.x + w1*dA.y + w2*dA.z + w3*dA.w + w4*dB.x + w5*dB.y + w6*dB.z + w7*dB.w;

    // ---- 4-step segmented sum reduce (width 16) ----
    #pragma unroll
    for (int off = 8; off > 0; off >>= 1) {
        a0 += __shfl_xor(a0, off, 16);
        a1 += __shfl_xor(a1, off, 16);
        a2 += __shfl_xor(a2, off, 16);
        ad += __shfl_xor(ad, off, 16);
    }

    if (sl == 0) {
        float* fo = feat_out + (size_t)ray * 3;
        fo[0] = a0;
        fo[1] = a1;
        fo[2] = a2;
        depth_out[ray] = ad;
    }

    // ---- per-wave depth max (4 rays/wave; ray max = last sample) ----
    float cand = (sl == 15) ? dB.w : 0.0f;
    cand = fmaxf(cand, __shfl_xor(cand, 16, 64));
    cand = fmaxf(cand, __shfl_xor(cand, 32, 64));
    if ((t & 63) == 15)
        wave_max[(blockIdx.x * 256 + t) >> 6] = cand;
}

// ---------------------------------------------------------------------------
// Epilogue: reduce per-wave maxes (L2-hot, 16384 entries) and scale
// depth_out in place. Every block computes the same gmax redundantly.
// ---------------------------------------------------------------------------
__global__ __launch_bounds__(256) void vr_epilogue(
    const float* __restrict__ wave_max, float* __restrict__ depth_out,
    int nw, int n_rays)
{
    const int t = threadIdx.x;

    float m = 0.0f;
    for (int i = t; i < nw; i += 256) m = fmaxf(m, wave_max[i]);
    #pragma unroll
    for (int off = 32; off > 0; off >>= 1)
        m = fmaxf(m, __shfl_xor(m, off, 64));

    __shared__ float wm[4];
    if ((t & 63) == 0) wm[t >> 6] = m;
    __syncthreads();
    float gm = fmaxf(fmaxf(wm[0], wm[1]), fmaxf(wm[2], wm[3]));

    int i = blockIdx.x * 256 + t;
    if (i < n_rays) depth_out[i] *= (1.0f / gm);
}

extern "C" void kernel_launch(void* const* d_in, const int* in_sizes, int n_in,
                              void* d_out, int out_size, void* d_ws, size_t ws_size,
                              hipStream_t stream)
{
    const float* depth   = (const float*)d_in[0];
    const float* density = (const float*)d_in[1];
    const float* feature = (const float*)d_in[2];

    const int n_rays = in_sizes[0] / N_PTS;

    float* out       = (float*)d_out;
    float* feat_out  = out;                        // [n_rays, 3]
    float* depth_out = out + (size_t)n_rays * 3;   // [n_rays, 1]
    float* wave_max  = (float*)d_ws;               // [n_rays/4] floats

    const int nb_main = n_rays / RPB;              // 4096 blocks
    const int nw      = n_rays / 4;                // 16384 wave maxes

    vr_main<<<nb_main, 256, 0, stream>>>(depth, density, feature,
                                         feat_out, depth_out, wave_max, n_rays);

    const int eb = (n_rays + 255) / 256;           // 256 blocks
    vr_epilogue<<<eb, 256, 0, stream>>>(wave_max, depth_out, nw, n_rays);
}

// Round 10
// 37.372 us; speedup vs baseline: 1.3596x; 1.1015x over previous
//
#include <hip/hip_runtime.h>

#define N_PTS 128
#define FAR_DELTA 1e10f
#define EPS 1e-10f
#define RPB 8   // rays per 256-thread block (32 lanes per ray)

// ---------------------------------------------------------------------------
// Volume rendering (round-6 structure + load-clause pinning).
// 32 lanes per ray, lane sl owns points 4sl..4sl+3; all 5 global loads are
// dwordx4 issued as ONE clause: the empty asm below consumes every loaded
// component, forcing a single s_waitcnt and keeping all 20 payload VGPRs
// live (rounds 6-9 showed the scheduler otherwise sinks the feature loads
// behind the scan, doubling per-wave exposed latency; VGPR_Count==20/32 was
// the tell).
//
// s at the global last point (sl==31, elem 3) is ~rho*1e10 and must NOT
// enter the scan totals ("inclusive - own" would cancel catastrophically);
// the reference's exclusive shift drops that element entirely, so we zero
// it in the total. No exclusive prefix ever contains it.
//
// depth_out written UNNORMALIZED; per-block depth max (8 rays, rows sorted
// so ray max = last sample) -> blk_max. Epilogue normalizes.
// ---------------------------------------------------------------------------
__global__ __launch_bounds__(256) void vr_main(
    const float* __restrict__ depth,    // [n_rays, 128]
    const float* __restrict__ density,  // [n_rays, 128, 1]
    const float* __restrict__ feature,  // [n_rays, 128, 3]
    float* __restrict__ feat_out,       // [n_rays, 3]
    float* __restrict__ depth_out,      // [n_rays, 1] (unnormalized here)
    float* __restrict__ blk_max,        // [gridDim.x]
    int n_rays)
{
    __shared__ float bmax[RPB];

    const int t   = threadIdx.x;
    const int q   = t >> 5;           // ray segment within block
    const int sl  = t & 31;           // lane within ray
    const int ray = blockIdx.x * RPB + q;

    // ---- 5 dwordx4 loads, one clause ----
    const float4* dp4 = (const float4*)(depth   + (size_t)ray * N_PTS);
    const float4* rp4 = (const float4*)(density + (size_t)ray * N_PTS);
    const float4* fp4 = (const float4*)(feature + (size_t)ray * N_PTS * 3);

    float4 d4 = dp4[sl];
    float4 r4 = rp4[sl];
    float4 f0 = fp4[sl * 3 + 0];   // {p0.r p0.g p0.b p1.r}
    float4 f1 = fp4[sl * 3 + 1];   // {p1.g p1.b p2.r p2.g}
    float4 f2 = fp4[sl * 3 + 2];   // {p2.b p3.r p3.g p3.b}

    // Pin every loaded component live HERE: forces the 5 loads to issue
    // back-to-back and complete once, before any dependent compute; the
    // register allocator can no longer sink the feature loads.
    asm volatile("" :
        "+v"(d4.x), "+v"(d4.y), "+v"(d4.z), "+v"(d4.w),
        "+v"(r4.x), "+v"(r4.y), "+v"(r4.z), "+v"(r4.w),
        "+v"(f0.x), "+v"(f0.y), "+v"(f0.z), "+v"(f0.w),
        "+v"(f1.x), "+v"(f1.y), "+v"(f1.z), "+v"(f1.w),
        "+v"(f2.x), "+v"(f2.y), "+v"(f2.z), "+v"(f2.w));

    // ray max depth = last sample (rows sorted ascending)
    if (sl == 31) bmax[q] = d4.w;

    // ---- deltas ----
    float nd = __shfl_down(d4.x, 1, 32);   // next lane's first depth
    float delta0 = d4.y - d4.x;
    float delta1 = d4.z - d4.y;
    float delta2 = d4.w - d4.z;
    float delta3 = (sl == 31) ? FAR_DELTA : (nd - d4.w);

    // ---- s = rho*(delta+eps), local prefix, segmented scan of totals ----
    float s0 = r4.x * (delta0 + EPS);
    float s1 = r4.y * (delta1 + EPS);
    float s2 = r4.z * (delta2 + EPS);
    float s3 = r4.w * (delta3 + EPS);

    float p1 = s0;
    float p2 = s0 + s1;
    float p3 = p2 + s2;
    float tt = p3 + ((sl == 31) ? 0.0f : s3);  // drop the huge last element

    float inc = tt;
    #pragma unroll
    for (int off = 1; off < 32; off <<= 1) {
        float n = __shfl_up(inc, off, 32);
        if (sl >= off) inc += n;
    }
    float excl = inc - tt;  // sum of totals of lanes 0..sl-1 (all benign)

    // ---- weights: trans * (1 - exp(-rho*delta + eps)) ----
    float w0 = __expf(-excl)        * (1.0f - __expf(fmaf(-r4.x, delta0, EPS)));
    float w1 = __expf(-(excl + p1)) * (1.0f - __expf(fmaf(-r4.y, delta1, EPS)));
    float w2 = __expf(-(excl + p2)) * (1.0f - __expf(fmaf(-r4.z, delta2, EPS)));
    float w3 = __expf(-(excl + p3)) * (1.0f - __expf(fmaf(-r4.w, delta3, EPS)));

    // ---- accumulate rgb + (unnormalized) depth ----
    float acc0 = w0 * f0.x + w1 * f0.w + w2 * f1.z + w3 * f2.y;
    float acc1 = w0 * f0.y + w1 * f1.x + w2 * f1.w + w3 * f2.z;
    float acc2 = w0 * f0.z + w1 * f1.y + w2 * f2.x + w3 * f2.w;
    float accd = w0 * d4.x + w1 * d4.y + w2 * d4.z + w3 * d4.w;

    // ---- 32-lane segmented sum reduce ----
    #pragma unroll
    for (int off = 16; off > 0; off >>= 1) {
        acc0 += __shfl_xor(acc0, off, 32);
        acc1 += __shfl_xor(acc1, off, 32);
        acc2 += __shfl_xor(acc2, off, 32);
        accd += __shfl_xor(accd, off, 32);
    }

    if (sl == 0 && ray < n_rays) {
        float* fo = feat_out + (size_t)ray * 3;
        fo[0] = acc0;
        fo[1] = acc1;
        fo[2] = acc2;
        depth_out[ray] = accd;
    }

    // ---- per-block depth max -> blk_max (plain store, no init needed) ----
    __syncthreads();
    if (t == 0) {
        float m = bmax[0];
        #pragma unroll
        for (int i = 1; i < RPB; ++i) m = fmaxf(m, bmax[i]);
        blk_max[blockIdx.x] = m;
    }
}

// ---------------------------------------------------------------------------
// Epilogue: reduce per-block maxes (L2-hot) and scale depth_out in place.
// Every block computes the same gmax redundantly, then scales its slice.
// ---------------------------------------------------------------------------
__global__ __launch_bounds__(256) void vr_epilogue(
    const float* __restrict__ blk_max, float* __restrict__ depth_out,
    int nb, int n_rays)
{
    const int t = threadIdx.x;

    float m = 0.0f;
    for (int i = t; i < nb; i += 256) m = fmaxf(m, blk_max[i]);
    #pragma unroll
    for (int off = 32; off > 0; off >>= 1)
        m = fmaxf(m, __shfl_xor(m, off, 64));

    __shared__ float wm[4];
    if ((t & 63) == 0) wm[t >> 6] = m;
    __syncthreads();
    float gm = fmaxf(fmaxf(wm[0], wm[1]), fmaxf(wm[2], wm[3]));

    int i = blockIdx.x * 256 + t;
    if (i < n_rays) depth_out[i] *= (1.0f / gm);
}

extern "C" void kernel_launch(void* const* d_in, const int* in_sizes, int n_in,
                              void* d_out, int out_size, void* d_ws, size_t ws_size,
                              hipStream_t stream)
{
    const float* depth   = (const float*)d_in[0];
    const float* density = (const float*)d_in[1];
    const float* feature = (const float*)d_in[2];

    const int n_rays = in_sizes[0] / N_PTS;

    float* out       = (float*)d_out;
    float* feat_out  = out;                        // [n_rays, 3]
    float* depth_out = out + (size_t)n_rays * 3;   // [n_rays, 1]
    float* blk_max   = (float*)d_ws;               // [n_rays/RPB] floats

    const int nb = n_rays / RPB;                   // 8192 blocks

    vr_main<<<nb, 256, 0, stream>>>(depth, density, feature,
                                    feat_out, depth_out, blk_max, n_rays);

    const int eb = (n_rays + 255) / 256;           // 256 blocks
    vr_epilogue<<<eb, 256, 0, stream>>>(blk_max, depth_out, nb, n_rays);
}